// Round 3
// baseline (27599.338 us; speedup 1.0000x reference)
//
#include <hip/hip_runtime.h>

typedef __bf16 bf16;
typedef __bf16 bf16x8 __attribute__((ext_vector_type(8)));
typedef float  f32x4  __attribute__((ext_vector_type(4)));

#define B_TOT 4096
#define T_SEQ 64
#define F_IN  32
#define C_CTY 64
#define L_LAT 256
#define W_HID 512
#define NT_OUT 8
#define SUBSTEPS 10
#define MB   16      // batch rows per block
#define NBLK 256     // one block per CU
#define NTHR 1024    // 16 waves

// Tsit5 tableau
constexpr float A21 = 0.161f;
constexpr float A31 = -0.008480655492356989f, A32 = 0.335480655492357f;
constexpr float A41 = 2.8971530571054935f, A42 = -6.359448489975075f, A43 = 4.362295432869581f;
constexpr float A51 = 5.325864828439257f, A52 = -11.748883564062828f, A53 = 7.4955393428898365f, A54 = -0.09249506636175525f;
constexpr float A61 = 5.86145544294642f, A62 = -12.92096931784711f, A63 = 8.159367898576159f, A64 = -0.071584973281401f, A65 = -0.028269050394068383f;
constexpr float BC1 = 0.09646076681806523f, BC2 = 0.01f, BC3 = 0.4798896504144996f;
constexpr float BC4 = 1.379008574103742f, BC5 = -3.290069515436081f, BC6 = 2.324710524099774f;
constexpr float DT = 0.1f;
constexpr float BROW[5][5] = {
    {A21, 0, 0, 0, 0},
    {A31, A32, 0, 0, 0},
    {A41, A42, A43, 0, 0},
    {A51, A52, A53, A54, 0},
    {A61, A62, A63, A64, A65}};
constexpr float FCF[6] = {BC1, BC2, BC3, BC4, BC5, BC6};

__device__ __forceinline__ f32x4 MFMA(bf16x8 a, bf16x8 b, f32x4 c) {
    return __builtin_amdgcn_mfma_f32_16x16x32_bf16(a, b, c, 0, 0, 0);
}
__device__ __forceinline__ float eluf(float x) { return x > 0.f ? x : __expf(x) - 1.f; }
__device__ __forceinline__ float sigm_f(float x) { return 1.f / (1.f + __expf(-x)); }
__device__ __forceinline__ float tanh_f(float x) { return 1.f - 2.f / (__expf(2.f * x) + 1.f); }

// scatter addr (elems) for value (feat n = w*16+lm, batch b) into 8-frag A-linear buffer
__device__ __forceinline__ int dpos16(int w, int lm, int b) {
    return ((w >> 1) * 64 + (2 * (w & 1) + (lm >> 3)) * 16 + b) * 8 + (lm & 7);
}
// scatter addr for value (feat n = (2w+nt)*16+lm, batch b) into 16-frag A-linear buffer
__device__ __forceinline__ int dpos32(int w, int nt, int lm, int b) {
    return (w * 64 + (2 * nt + (lm >> 3)) * 16 + b) * 8 + (lm & 7);
}

// ---- one Tsit5 stage (3 layers, 3 barriers), weights in registers ----
template<int STAGE>
__device__ __forceinline__ void ode_stage(
    bf16* __restrict__ Yb, bf16* __restrict__ Ab, bf16* __restrict__ Bb,
    float* __restrict__ Ydec,
    const bf16x8 (&w0r)[2][8], const bf16x8 (&w1r)[2][16], const bf16x8 (&w2r)[16],
    const float (&b0r)[2], const float (&b1r)[2], float b2r,
    f32x4& yreg, f32x4 (&kreg)[6], int w, int lane, bool dec) {
    const int lm = lane & 15, q4 = (lane >> 4) << 2;
    const f32x4 z = {0.f, 0.f, 0.f, 0.f};

    // ---- L0: h1 = elu(y_stage @ W0^T + b0): read Yb (8 frags), write Ab ----
    f32x4 acc0[2] = {z, z};
    {
        bf16x8 a[8];
        #pragma unroll
        for (int kk = 0; kk < 8; ++kk) a[kk] = *(const bf16x8*)&Yb[(kk * 64 + lane) * 8];
        #pragma unroll
        for (int kk = 0; kk < 8; ++kk) {
            acc0[0] = MFMA(a[kk], w0r[0][kk], acc0[0]);
            acc0[1] = MFMA(a[kk], w0r[1][kk], acc0[1]);
        }
    }
    #pragma unroll
    for (int nt = 0; nt < 2; ++nt)
        #pragma unroll
        for (int r = 0; r < 4; ++r)
            Ab[dpos32(w, nt, lm, q4 + r)] = (bf16)eluf(acc0[nt][r] + b0r[nt]);
    __syncthreads();

    // ---- L1: h2 = elu(h1 @ W1^T + b1): read Ab (16 frags), write Bb ----
    f32x4 acc1[2] = {z, z};
    #pragma unroll
    for (int h2 = 0; h2 < 2; ++h2) {
        bf16x8 a[8];
        #pragma unroll
        for (int kk = 0; kk < 8; ++kk) a[kk] = *(const bf16x8*)&Ab[((h2 * 8 + kk) * 64 + lane) * 8];
        #pragma unroll
        for (int kk = 0; kk < 8; ++kk) {
            acc1[0] = MFMA(a[kk], w1r[0][h2 * 8 + kk], acc1[0]);
            acc1[1] = MFMA(a[kk], w1r[1][h2 * 8 + kk], acc1[1]);
        }
    }
    #pragma unroll
    for (int nt = 0; nt < 2; ++nt)
        #pragma unroll
        for (int r = 0; r < 4; ++r)
            Bb[dpos32(w, nt, lm, q4 + r)] = (bf16)eluf(acc1[nt][r] + b1r[nt]);
    __syncthreads();

    // ---- L2: k = h2 @ W2^T + b2: read Bb (16 frags) -> kreg; build y_stage -> Yb ----
    f32x4 acc2 = z;
    #pragma unroll
    for (int h2 = 0; h2 < 2; ++h2) {
        bf16x8 a[8];
        #pragma unroll
        for (int kk = 0; kk < 8; ++kk) a[kk] = *(const bf16x8*)&Bb[((h2 * 8 + kk) * 64 + lane) * 8];
        #pragma unroll
        for (int kk = 0; kk < 8; ++kk) acc2 = MFMA(a[kk], w2r[h2 * 8 + kk], acc2);
    }
    #pragma unroll
    for (int r = 0; r < 4; ++r) kreg[STAGE][r] = acc2[r] + b2r;

    f32x4 yst;
    if constexpr (STAGE < 5) {
        yst = yreg;
        #pragma unroll
        for (int i = 0; i <= STAGE; ++i) {
            const float c = DT * BROW[STAGE][i];
            #pragma unroll
            for (int r = 0; r < 4; ++r) yst[r] += c * kreg[i][r];
        }
    } else {
        #pragma unroll
        for (int i = 0; i < 6; ++i) {
            const float c = DT * FCF[i];
            #pragma unroll
            for (int r = 0; r < 4; ++r) yreg[r] += c * kreg[i][r];
        }
        yst = yreg;
        if (dec) {
            #pragma unroll
            for (int r = 0; r < 4; ++r)
                Ydec[(q4 + r) * 260 + w * 16 + lm] = yreg[r];
        }
    }
    #pragma unroll
    for (int r = 0; r < 4; ++r)
        Yb[dpos16(w, lm, q4 + r)] = (bf16)yst[r];
    __syncthreads();
}

__global__ void __launch_bounds__(NTHR, 4)
k_main(const float* __restrict__ x_seq, const int* __restrict__ cidx,
       const float* __restrict__ b_n, const float* __restrict__ b0,
       const float* __restrict__ b1, const float* __restrict__ b2,
       const float* __restrict__ W_dec, const float* __restrict__ b_dec,
       const bf16* __restrict__ WihP, const bf16* __restrict__ WhhP,
       const bf16* __restrict__ W0p, const bf16* __restrict__ W1p,
       const bf16* __restrict__ W2p, const float* __restrict__ bias_c,
       float* __restrict__ out, int H) {
    __shared__ __align__(16) bf16 sYb[8 * 512];        // y_stage frags
    __shared__ __align__(16) bf16 sAb[16 * 512];       // h1 frags
    __shared__ __align__(16) bf16 sBb[16 * 512];       // h2 frags
    __shared__ __align__(16) bf16 sHx[2 * 9 * 512];    // GRU [h|x] frags, dbuf
    __shared__ __align__(16) float sYdec[MB * 260];    // f32 y for decode
    __shared__ __align__(16) float sWdec[NT_OUT * L_LAT];
    __shared__ float sBdec[NT_OUT];

    const int tid = threadIdx.x, w = tid >> 6, lane = tid & 63;
    const int lm = lane & 15, q = lane >> 4, q4 = q << 2;
    const int b0row = blockIdx.x * MB;

    for (int i = tid; i < NT_OUT * L_LAT; i += NTHR) sWdec[i] = W_dec[i];
    if (tid < NT_OUT) sBdec[tid] = b_dec[tid];

    // ---------- GRU phase: weights + gate biases in registers ----------
    const int nf = w * 16 + lm;                        // this lane's feature
    float bcr[4], bcz[4], bcn[4];
    {
        #pragma unroll
        for (int r = 0; r < 4; ++r) {
            const int c = cidx[b0row + q4 + r];
            bcr[r] = bias_c[(size_t)c * 768 + nf];
            bcz[r] = bias_c[(size_t)c * 768 + 256 + nf];
            bcn[r] = bias_c[(size_t)c * 768 + 512 + nf];
        }
    }
    const float bnr = b_n[nf];

    bf16x8 whr[3][8], wxr[3];
    {
        const int tiles[3] = {w, 16 + w, 32 + w};
        #pragma unroll
        for (int j = 0; j < 3; ++j) {
            wxr[j] = *(const bf16x8*)&WihP[(size_t)tiles[j] * 512 + lane * 8];
            #pragma unroll
            for (int kk = 0; kk < 8; ++kk)
                whr[j][kk] = *(const bf16x8*)&WhhP[((size_t)tiles[j] * 8 + kk) * 512 + lane * 8];
        }
    }

    f32x4 hreg = {0.f, 0.f, 0.f, 0.f};
    f32x4 xra = {0.f, 0.f, 0.f, 0.f}, xrb = {0.f, 0.f, 0.f, 0.f};

    // prologue: scatter h=0 into buf0; wave15 stages x(0), prefetches x(1)
    if (w == 15) {
        const float* xs = &x_seq[((size_t)(b0row + (lane & 15)) * T_SEQ + 0) * F_IN + 8 * q];
        xra = *(const f32x4*)xs;
        xrb = *(const f32x4*)(xs + 4);
    }
    #pragma unroll
    for (int r = 0; r < 4; ++r) sHx[dpos16(w, lm, q4 + r)] = (bf16)0.f;
    if (w == 15) {
        bf16x8 ox;
        #pragma unroll
        for (int j = 0; j < 4; ++j) { ox[j] = (bf16)xra[j]; ox[4 + j] = (bf16)xrb[j]; }
        *(bf16x8*)&sHx[(8 * 64 + lane) * 8] = ox;
        const float* xs = &x_seq[((size_t)(b0row + (lane & 15)) * T_SEQ + 1) * F_IN + 8 * q];
        xra = *(const f32x4*)xs;
        xrb = *(const f32x4*)(xs + 4);
    }

    for (int t = 0; t < T_SEQ; ++t) {
        const bf16* hx = sHx + (t & 1) * (9 * 512);
        __syncthreads();
        bf16x8 a[9];
        #pragma unroll
        for (int kk = 0; kk < 9; ++kk) a[kk] = *(const bf16x8*)&hx[(kk * 64 + lane) * 8];
        const f32x4 z = {0.f, 0.f, 0.f, 0.f};
        f32x4 aH[3] = {z, z, z}, aX[3] = {z, z, z};
        #pragma unroll
        for (int j = 0; j < 3; ++j) aX[j] = MFMA(a[8], wxr[j], aX[j]);
        #pragma unroll
        for (int kk = 0; kk < 8; ++kk)
            #pragma unroll
            for (int j = 0; j < 3; ++j) aH[j] = MFMA(a[kk], whr[j][kk], aH[j]);
        #pragma unroll
        for (int r = 0; r < 4; ++r) {
            const float rg = sigm_f(aH[0][r] + aX[0][r] + bcr[r]);
            const float zg = sigm_f(aH[1][r] + aX[1][r] + bcz[r]);
            const float nn = tanh_f(aX[2][r] + bcn[r] + rg * (aH[2][r] + bnr));
            hreg[r] = nn + zg * (hreg[r] - nn);
        }
        if (t + 1 < T_SEQ) {
            bf16* hxn = sHx + ((t + 1) & 1) * (9 * 512);
            #pragma unroll
            for (int r = 0; r < 4; ++r) hxn[dpos16(w, lm, q4 + r)] = (bf16)hreg[r];
            if (w == 15) {
                bf16x8 ox;
                #pragma unroll
                for (int j = 0; j < 4; ++j) { ox[j] = (bf16)xra[j]; ox[4 + j] = (bf16)xrb[j]; }
                *(bf16x8*)&hxn[(8 * 64 + lane) * 8] = ox;
                const int tn = (t + 2 < T_SEQ) ? t + 2 : T_SEQ - 1;
                const float* xs = &x_seq[((size_t)(b0row + (lane & 15)) * T_SEQ + tn) * F_IN + 8 * q];
                xra = *(const f32x4*)xs;
                xrb = *(const f32x4*)(xs + 4);
            }
        }
    }

    // ---------- load ODE weights into registers (GRU regs now dead) ----------
    asm volatile("" ::: "memory");
    bf16x8 w0r[2][8], w1r[2][16], w2r[16];
    #pragma unroll
    for (int nt = 0; nt < 2; ++nt)
        #pragma unroll
        for (int kk = 0; kk < 8; ++kk)
            w0r[nt][kk] = *(const bf16x8*)&W0p[(((size_t)(2 * w + nt)) * 8 + kk) * 512 + lane * 8];
    #pragma unroll
    for (int nt = 0; nt < 2; ++nt)
        #pragma unroll
        for (int kk = 0; kk < 16; ++kk)
            w1r[nt][kk] = *(const bf16x8*)&W1p[(((size_t)(2 * w + nt)) * 16 + kk) * 512 + lane * 8];
    #pragma unroll
    for (int kk = 0; kk < 16; ++kk)
        w2r[kk] = *(const bf16x8*)&W2p[((size_t)w * 16 + kk) * 512 + lane * 8];

    float b0r[2], b1r[2];
    #pragma unroll
    for (int nt = 0; nt < 2; ++nt) {
        b0r[nt] = b0[(2 * w + nt) * 16 + lm];
        b1r[nt] = b1[(2 * w + nt) * 16 + lm];
    }
    const float b2r = b2[w * 16 + lm];

    f32x4 yreg = hreg;
    f32x4 kreg[6];
    #pragma unroll
    for (int r = 0; r < 4; ++r)
        sYb[dpos16(w, lm, q4 + r)] = (bf16)yreg[r];
    __syncthreads();

    // ---------- Neural ODE (Tsit5) + decode ----------
    for (int u = 0; u < H; ++u) {
        for (int s = 0; s < SUBSTEPS; ++s) {
            const bool dec = (s == SUBSTEPS - 1);
            ode_stage<0>(sYb, sAb, sBb, sYdec, w0r, w1r, w2r, b0r, b1r, b2r, yreg, kreg, w, lane, false);
            ode_stage<1>(sYb, sAb, sBb, sYdec, w0r, w1r, w2r, b0r, b1r, b2r, yreg, kreg, w, lane, false);
            ode_stage<2>(sYb, sAb, sBb, sYdec, w0r, w1r, w2r, b0r, b1r, b2r, yreg, kreg, w, lane, false);
            ode_stage<3>(sYb, sAb, sBb, sYdec, w0r, w1r, w2r, b0r, b1r, b2r, yreg, kreg, w, lane, false);
            ode_stage<4>(sYb, sAb, sBb, sYdec, w0r, w1r, w2r, b0r, b1r, b2r, yreg, kreg, w, lane, false);
            ode_stage<5>(sYb, sAb, sBb, sYdec, w0r, w1r, w2r, b0r, b1r, b2r, yreg, kreg, w, lane, dec);
        }
        // decode (sYdec written before stage5's final barrier)
        if (tid < MB * NT_OUT) {
            const int m = tid >> 3, tt = tid & 7;
            float acc = sBdec[tt];
            const float* wd = &sWdec[tt * L_LAT];
            #pragma unroll 4
            for (int l = 0; l < L_LAT; l += 4) {
                f32x4 yv = *(const f32x4*)&sYdec[m * 260 + l];
                acc += yv[0] * wd[l] + yv[1] * wd[l + 1] + yv[2] * wd[l + 2] + yv[3] * wd[l + 3];
            }
            out[((size_t)(b0row + m) * H + u) * NT_OUT + tt] = acc;
        }
    }
}

// Pack fp32 weight [OUT][Ksrc] (cols koff..koff+K) into MFMA-fragment order bf16:
// frag f = c*(K/32)+kk; lane's 8 elems = row c*16+(lane&15), k = kk*32+(lane>>4)*8+j
__global__ void k_pack(const float* __restrict__ src, bf16* __restrict__ dst,
                       int OUT, int K, int Ksrc, int koff) {
    const int total = (OUT * K) >> 3;
    for (int g = blockIdx.x * blockDim.x + threadIdx.x; g < total; g += gridDim.x * blockDim.x) {
        const int lane = g & 63, f = g >> 6;
        const int KK = K >> 5;
        const int kk = f % KK, c = f / KK;
        const int col = c * 16 + (lane & 15);
        const int k0 = kk * 32 + ((lane >> 4) << 3);
        bf16x8 o;
        #pragma unroll
        for (int j = 0; j < 8; ++j) o[j] = (bf16)src[(size_t)col * Ksrc + koff + k0 + j];
        *(bf16x8*)&dst[(size_t)g * 8] = o;
    }
}

__global__ void k_bias(const float* __restrict__ W_ih, const float* __restrict__ b_ih,
                       float* __restrict__ bias_c) {
    const int i = blockIdx.x * blockDim.x + threadIdx.x;
    if (i < C_CTY * 3 * L_LAT) {
        const int c = i / (3 * L_LAT), n = i - c * (3 * L_LAT);
        bias_c[i] = W_ih[(size_t)n * (F_IN + C_CTY) + F_IN + c] + b_ih[n];
    }
}

extern "C" void kernel_launch(void* const* d_in, const int* in_sizes, int n_in,
                              void* d_out, int out_size, void* d_ws, size_t ws_size,
                              hipStream_t stream) {
    const float* x_seq = (const float*)d_in[0];
    const int*   cidx  = (const int*)d_in[1];
    const float* W_ih  = (const float*)d_in[3];
    const float* W_hh  = (const float*)d_in[4];
    const float* b_ih  = (const float*)d_in[5];
    const float* b_n   = (const float*)d_in[6];
    const float* W0    = (const float*)d_in[7];
    const float* b0    = (const float*)d_in[8];
    const float* W1    = (const float*)d_in[9];
    const float* b1    = (const float*)d_in[10];
    const float* W2    = (const float*)d_in[11];
    const float* b2    = (const float*)d_in[12];
    const float* W_dec = (const float*)d_in[13];
    const float* b_dec = (const float*)d_in[14];
    float* out = (float*)d_out;
    const int H = out_size / (B_TOT * NT_OUT);

    char* ws = (char*)d_ws;
    bf16*  W0p    = (bf16*)(ws + 0);         // 512*256 bf16 = 262144 B
    bf16*  W1p    = (bf16*)(ws + 262144);    // 512*512      = 524288 B
    bf16*  W2p    = (bf16*)(ws + 786432);    // 256*512      = 262144 B
    bf16*  WhhP   = (bf16*)(ws + 1048576);   // 768*256      = 393216 B
    bf16*  WihP   = (bf16*)(ws + 1441792);   // 768*32       = 49152 B
    float* bias_c = (float*)(ws + 1490944);  // 64*768 f32   = 196608 B

    k_pack<<<64, 256, 0, stream>>>(W0, W0p, 512, 256, 256, 0);
    k_pack<<<128, 256, 0, stream>>>(W1, W1p, 512, 512, 512, 0);
    k_pack<<<64, 256, 0, stream>>>(W2, W2p, 256, 512, 512, 0);
    k_pack<<<96, 256, 0, stream>>>(W_hh, WhhP, 768, 256, 256, 0);
    k_pack<<<12, 256, 0, stream>>>(W_ih, WihP, 768, 32, 96, 0);
    k_bias<<<(C_CTY * 3 * L_LAT + 255) / 256, 256, 0, stream>>>(W_ih, b_ih, bias_c);

    k_main<<<NBLK, NTHR, 0, stream>>>(x_seq, cidx, b_n, b0, b1, b2, W_dec, b_dec,
                                      WihP, WhhP, W0p, W1p, W2p, bias_c, out, H);
}